// Round 5
// baseline (1809.501 us; speedup 1.0000x reference)
//
#include <hip/hip_runtime.h>
#include <math.h>

#define N_   8
#define C_   64
#define H_   128
#define W_   128
#define HW_  (H_ * W_)
#define CHW_ (C_ * HW_)
#define CI_TILE 8
#define TILE 16
#define HALO (TILE + 2)          // 18
#define LDS_STRIDE 20            // 80B x-rows: 16B-aligned b128 reads, 2-way-conflict-free
#define WROW 12                  // weight row pad 9->12 floats (48B, 16B-aligned)
#define BN_EPS 1e-5
#define POW_EPS 1e-12f

// Kernel 1: y = adder2d(x, W) + x, with fused per-channel sum/sumsq stats.
// CI_TILE=8 -> LDS 23.8KB -> 6 blocks/CU capacity; grid 1024 -> ALL blocks
// co-resident (4/CU, 16 waves/CU, no tail quantization — round-4 lesson).
// Weights staged in LDS (wave-broadcast reads, loaded just-in-time);
// __launch_bounds__(256,4) caps VGPR at 128 (liveness ~85: acc32+xr18+w12+addr).
// Block: 256 thr = 64 px-threads x 4 co-groups (8 co each).
//   lane: r = lane&15 (row), s = lane>>4 (4-px w segment).
// Grid: (64 tiles, N, 2 co-halves); z-pairs differ by 512 in linear id == 0 mod 8
//   -> same XCD -> shared L2 for the x-halo re-read.
__global__ __launch_bounds__(256, 4) void adder_kernel(
    const float* __restrict__ x, const float* __restrict__ weight,
    float* __restrict__ y, double* __restrict__ sums)
{
    __shared__ __align__(16) float sx[CI_TILE][HALO][LDS_STRIDE];
    __shared__ __align__(16) float sw[32 * CI_TILE * WROW];  // [co][ci][12]

    const int lane = threadIdx.x & 63;
    const int cog  = threadIdx.x >> 6;    // 0..3, wave-uniform by construction
    const int r    = lane & 15;           // row (fast)
    const int s    = lane >> 4;           // 4-px w segment
    const int tile = blockIdx.x;
    const int n    = blockIdx.y;
    const int co0  = blockIdx.z * 32;
    const int h0 = (tile >> 3) * TILE;
    const int w0 = (tile & 7) * TILE;

    float acc[4][8];
#pragma unroll
    for (int p = 0; p < 4; ++p)
#pragma unroll
        for (int co = 0; co < 8; ++co) acc[p][co] = 0.f;

    const float* xn = x + n * CHW_;

    for (int cb = 0; cb < C_; cb += CI_TILE) {
        __syncthreads();

        // Stage x: CI_TILE x 18 x 18 halo, zero-filled outside image
        // (zero padding contributes |0 - w| at borders). 2592 elems.
        for (int idx = threadIdx.x; idx < CI_TILE * HALO * HALO; idx += 256) {
            int ci  = idx / (HALO * HALO);
            int rem = idx - ci * (HALO * HALO);
            int rr  = rem / HALO;
            int cc  = rem - rr * HALO;
            int gh  = h0 + rr - 1;
            int gw  = w0 + cc - 1;
            float v = 0.f;
            if ((unsigned)gh < (unsigned)H_ && (unsigned)gw < (unsigned)W_)
                v = xn[(cb + ci) * HW_ + gh * W_ + gw];
            sx[ci][rr][cc] = v;
        }

        // Stage weights: 32 co x 8 ci x 9 = 2304 elems = 9/thread, coalesced.
#pragma unroll
        for (int t = 0; t < 9; ++t) {
            int idx = threadIdx.x + t * 256;
            int co  = idx / (CI_TILE * 9);
            int rem = idx - co * (CI_TILE * 9);
            int ci  = rem / 9;
            int k   = rem - ci * 9;
            sw[(co * CI_TILE + ci) * WROW + k] =
                weight[(co0 + co) * (C_ * 9) + (cb + ci) * 9 + k];
        }
        __syncthreads();

#pragma unroll 1
        for (int ci = 0; ci < CI_TILE; ++ci) {
            // x window rows r..r+2, cols 4s..4s+5 (aligned b128 + b64)
            float xr[3][6];
#pragma unroll
            for (int kh = 0; kh < 3; ++kh) {
                const float* row = &sx[ci][r + kh][4 * s];
                float4 a = *reinterpret_cast<const float4*>(row);
                float2 b = *reinterpret_cast<const float2*>(row + 4);
                xr[kh][0] = a.x; xr[kh][1] = a.y; xr[kh][2] = a.z; xr[kh][3] = a.w;
                xr[kh][4] = b.x; xr[kh][5] = b.y;
            }

#pragma unroll
            for (int co = 0; co < 8; ++co) {
                // Wave-broadcast LDS reads, just-in-time (12 transient regs)
                const float* wc = &sw[((cog * 8 + co) * CI_TILE + ci) * WROW];
                float4 wa = *reinterpret_cast<const float4*>(wc);
                float4 wb = *reinterpret_cast<const float4*>(wc + 4);
                float  w8 = wc[8];
#pragma unroll
                for (int p = 0; p < 4; ++p) {
                    float t = fabsf(xr[0][p]     - wa.x) + fabsf(xr[0][p + 1] - wa.y)
                            + fabsf(xr[0][p + 2] - wa.z) + fabsf(xr[1][p]     - wa.w)
                            + fabsf(xr[1][p + 1] - wb.x) + fabsf(xr[1][p + 2] - wb.y)
                            + fabsf(xr[2][p]     - wb.z) + fabsf(xr[2][p + 1] - wb.w)
                            + fabsf(xr[2][p + 2] - w8);
                    acc[p][co] += t;
                }
            }
        }
    }

    // Epilogue: y = -acc + residual; fused per-co sum/sumsq partials.
    const int pix = (h0 + r) * W_ + w0 + 4 * s;
    float bs[8], bss[8];
#pragma unroll
    for (int co = 0; co < 8; ++co) {
        const int coc = co0 + cog * 8 + co;
        float4 res = *reinterpret_cast<const float4*>(xn + coc * HW_ + pix);
        float4 o;
        o.x = -acc[0][co] + res.x;
        o.y = -acc[1][co] + res.y;
        o.z = -acc[2][co] + res.z;
        o.w = -acc[3][co] + res.w;
        *reinterpret_cast<float4*>(y + n * CHW_ + coc * HW_ + pix) = o;
        bs[co]  = o.x + o.y + o.z + o.w;
        bss[co] = o.x * o.x + o.y * o.y + o.z * o.z + o.w * o.w;
    }
    // Wave reduction (64 lanes = all pixels of this wave's co-group).
#pragma unroll
    for (int off = 32; off > 0; off >>= 1) {
#pragma unroll
        for (int co = 0; co < 8; ++co) {
            bs[co]  += __shfl_down(bs[co],  off);
            bss[co] += __shfl_down(bss[co], off);
        }
    }
    if (lane == 0) {
#pragma unroll
        for (int co = 0; co < 8; ++co) {
            const int coc = co0 + cog * 8 + co;
            atomicAdd(&sums[coc],      (double)bs[co]);
            atomicAdd(&sums[C_ + coc], (double)bss[co]);
        }
    }
}

// Kernel 2: per-channel scale/shift from batch stats.
__global__ void finalize_kernel(const double* __restrict__ sums,
                                const float* __restrict__ gamma,
                                const float* __restrict__ beta,
                                float* __restrict__ sc)
{
    const int c = threadIdx.x;  // 64 threads
    const double cnt = (double)(N_ * HW_);
    double mean = sums[c] / cnt;
    double var  = sums[C_ + c] / cnt - mean * mean;
    float inv   = (float)(1.0 / sqrt(var + (double)BN_EPS));
    float scale = gamma[c] * inv;
    float shift = beta[c] - (float)mean * scale;
    sc[c]      = scale;
    sc[C_ + c] = shift;
}

// Kernel 3: in-place BN affine + power activation, float4 vectorized.
// alpha==1 (uniform scalar branch): sign(t)*(|t|+eps)^1 == t + sign(t)*eps, exact.
__global__ __launch_bounds__(256) void apply_kernel(
    float* __restrict__ y, const float* __restrict__ sc,
    const float* __restrict__ alpha_p)
{
    const int idx = blockIdx.x * 256 + threadIdx.x;   // float4 index
    const float alpha = alpha_p[0];
    const int e0 = idx * 4;
    const int c = (e0 / HW_) & (C_ - 1);
    const float scale = sc[c];
    const float shift = sc[C_ + c];

    float4 v = reinterpret_cast<float4*>(y)[idx];
    float* pv = reinterpret_cast<float*>(&v);
    if (alpha == 1.0f) {
#pragma unroll
        for (int i = 0; i < 4; ++i) {
            float t = pv[i] * scale + shift;
            float sgn = (t > 0.f) ? 1.f : ((t < 0.f) ? -1.f : 0.f);
            pv[i] = t + sgn * POW_EPS;
        }
    } else {
#pragma unroll
        for (int i = 0; i < 4; ++i) {
            float t = pv[i] * scale + shift;
            float sgn = (t > 0.f) ? 1.f : ((t < 0.f) ? -1.f : 0.f);
            pv[i] = sgn * powf(fabsf(t) + POW_EPS, alpha);
        }
    }
    reinterpret_cast<float4*>(y)[idx] = v;
}

extern "C" void kernel_launch(void* const* d_in, const int* in_sizes, int n_in,
                              void* d_out, int out_size, void* d_ws, size_t ws_size,
                              hipStream_t stream)
{
    const float* x      = (const float*)d_in[0];
    const float* weight = (const float*)d_in[1];
    const float* gamma  = (const float*)d_in[2];
    const float* beta   = (const float*)d_in[3];
    const float* alpha  = (const float*)d_in[4];
    float* out = (float*)d_out;

    double* sums = (double*)d_ws;                                // 128 doubles
    float*  sc   = (float*)((char*)d_ws + 128 * sizeof(double)); // 128 floats

    hipMemsetAsync(d_ws, 0, 128 * sizeof(double), stream);

    adder_kernel<<<dim3(64, N_, 2), 256, 0, stream>>>(x, weight, out, sums);
    finalize_kernel<<<1, C_, 0, stream>>>(sums, gamma, beta, sc);

    const int n4 = (N_ * CHW_) / 4;
    apply_kernel<<<n4 / 256, 256, 0, stream>>>(out, sc, alpha);
}

// Round 6
// 1372.074 us; speedup vs baseline: 1.3188x; 1.3188x over previous
//
#include <hip/hip_runtime.h>
#include <math.h>

#define N_   8
#define C_   64
#define H_   128
#define W_   128
#define HW_  (H_ * W_)
#define CHW_ (C_ * HW_)
#define CI_TILE 8
#define TILE 16
#define HALO (TILE + 2)          // 18
#define LDS_STRIDE 20            // 80B rows: 16B-aligned b128 reads, conflict-free
#define BN_EPS 1e-5
#define POW_EPS 1e-12f

// Kernel 1: y = adder2d(x, W) + x, fused per-channel sum/sumsq stats.
//
// Rounds 2-5 lesson: the backend insists on a 64-VGPR budget (8 waves/EU)
// and spills acc when per-thread liveness exceeds it. So: liveness < 64 by
// construction. Thread = 4 px x 4 co -> acc 16 + window 18 + misc ~50 regs.
// Weights: fully scalar addressing (readfirstlane wave id) -> s_load into
// SGPRs (36/iter), zero VGPR cost, zero LDS-pipe contention (the R4/R5 LDS
// weight broadcasts made the per-CU LDS unit co-limiting).
// Block: 256 thr = 4 waves; wave w handles co [z*16 + 4w, +4).
//   lane: r = lane&15 (row), s = lane>>4 (4-px w segment).
// Grid: (64 tiles, N, 4 co-quarters) = 2048 blocks = exactly 8 blocks/CU
//   (LDS 11.5KB, VGPR<=64) -> full residency, no tail.
__global__ __launch_bounds__(256, 8) void adder_kernel(
    const float* __restrict__ x, const float* __restrict__ weight,
    float* __restrict__ y, double* __restrict__ sums)
{
    __shared__ __align__(16) float sx[CI_TILE][HALO][LDS_STRIDE];  // 11.52 KB

    const int lane = threadIdx.x & 63;
    const int cog  = __builtin_amdgcn_readfirstlane(threadIdx.x >> 6); // SGPR
    const int r    = lane & 15;           // row (fast lane dim)
    const int s    = lane >> 4;           // 4-px w segment
    const int tile = blockIdx.x;
    const int n    = blockIdx.y;
    const int co_base = blockIdx.z * 16 + cog * 4;   // fully scalar
    const int h0 = (tile >> 3) * TILE;
    const int w0 = (tile & 7) * TILE;

    float acc[4][4];
#pragma unroll
    for (int p = 0; p < 4; ++p)
#pragma unroll
        for (int co = 0; co < 4; ++co) acc[p][co] = 0.f;

    const float* xn = x + n * CHW_;

    for (int cb = 0; cb < C_; cb += CI_TILE) {
        __syncthreads();
        // Stage x: CI_TILE x 18 x 18 halo, zero-filled outside image
        // (zero padding contributes |0 - w| at borders). 2592 elems.
        for (int idx = threadIdx.x; idx < CI_TILE * HALO * HALO; idx += 256) {
            int ci  = idx / (HALO * HALO);
            int rem = idx - ci * (HALO * HALO);
            int rr  = rem / HALO;
            int cc  = rem - rr * HALO;
            int gh  = h0 + rr - 1;
            int gw  = w0 + cc - 1;
            float v = 0.f;
            if ((unsigned)gh < (unsigned)H_ && (unsigned)gw < (unsigned)W_)
                v = xn[(cb + ci) * HW_ + gh * W_ + gw];
            sx[ci][rr][cc] = v;
        }
        __syncthreads();

#pragma unroll 1
        for (int ci = 0; ci < CI_TILE; ++ci) {
            // x window rows r..r+2, cols 4s..4s+5 (aligned b128 + b64)
            float xr[3][6];
#pragma unroll
            for (int kh = 0; kh < 3; ++kh) {
                const float* row = &sx[ci][r + kh][4 * s];
                float4 a = *reinterpret_cast<const float4*>(row);
                float2 b = *reinterpret_cast<const float2*>(row + 4);
                xr[kh][0] = a.x; xr[kh][1] = a.y; xr[kh][2] = a.z; xr[kh][3] = a.w;
                xr[kh][4] = b.x; xr[kh][5] = b.y;
            }

            // Scalar weight base: s_load -> SGPR broadcast (36 dwords/iter).
            const float* wp = weight + co_base * (C_ * 9) + (cb + ci) * 9;
#pragma unroll
            for (int co = 0; co < 4; ++co) {
                const float* wc = wp + co * (C_ * 9);
                float wv[9];
#pragma unroll
                for (int k = 0; k < 9; ++k) wv[k] = wc[k];
#pragma unroll
                for (int p = 0; p < 4; ++p) {
                    float t = fabsf(xr[0][p]     - wv[0]) + fabsf(xr[0][p + 1] - wv[1])
                            + fabsf(xr[0][p + 2] - wv[2]) + fabsf(xr[1][p]     - wv[3])
                            + fabsf(xr[1][p + 1] - wv[4]) + fabsf(xr[1][p + 2] - wv[5])
                            + fabsf(xr[2][p]     - wv[6]) + fabsf(xr[2][p + 1] - wv[7])
                            + fabsf(xr[2][p + 2] - wv[8]);
                    acc[p][co] += t;
                }
            }
        }
    }

    // Epilogue: y = -acc + residual; fused per-co sum/sumsq partials.
    const int pix = (h0 + r) * W_ + w0 + 4 * s;
    float bs[4], bss[4];
#pragma unroll
    for (int co = 0; co < 4; ++co) {
        const int coc = co_base + co;
        float4 res = *reinterpret_cast<const float4*>(xn + coc * HW_ + pix);
        float4 o;
        o.x = -acc[0][co] + res.x;
        o.y = -acc[1][co] + res.y;
        o.z = -acc[2][co] + res.z;
        o.w = -acc[3][co] + res.w;
        *reinterpret_cast<float4*>(y + n * CHW_ + coc * HW_ + pix) = o;
        bs[co]  = o.x + o.y + o.z + o.w;
        bss[co] = o.x * o.x + o.y * o.y + o.z * o.z + o.w * o.w;
    }
    // Wave reduction (64 lanes = all 256 px of this wave's co-group).
#pragma unroll
    for (int off = 32; off > 0; off >>= 1) {
#pragma unroll
        for (int co = 0; co < 4; ++co) {
            bs[co]  += __shfl_down(bs[co],  off);
            bss[co] += __shfl_down(bss[co], off);
        }
    }
    if (lane == 0) {
#pragma unroll
        for (int co = 0; co < 4; ++co) {
            const int coc = co_base + co;
            atomicAdd(&sums[coc],      (double)bs[co]);
            atomicAdd(&sums[C_ + coc], (double)bss[co]);
        }
    }
}

// Kernel 2: per-channel scale/shift from batch stats.
__global__ void finalize_kernel(const double* __restrict__ sums,
                                const float* __restrict__ gamma,
                                const float* __restrict__ beta,
                                float* __restrict__ sc)
{
    const int c = threadIdx.x;  // 64 threads
    const double cnt = (double)(N_ * HW_);
    double mean = sums[c] / cnt;
    double var  = sums[C_ + c] / cnt - mean * mean;
    float inv   = (float)(1.0 / sqrt(var + (double)BN_EPS));
    float scale = gamma[c] * inv;
    float shift = beta[c] - (float)mean * scale;
    sc[c]      = scale;
    sc[C_ + c] = shift;
}

// Kernel 3: in-place BN affine + power activation, float4 vectorized.
// alpha==1 (uniform branch): sign(t)*(|t|+eps)^1 == t + sign(t)*eps, exact.
__global__ __launch_bounds__(256) void apply_kernel(
    float* __restrict__ y, const float* __restrict__ sc,
    const float* __restrict__ alpha_p)
{
    const int idx = blockIdx.x * 256 + threadIdx.x;   // float4 index
    const float alpha = alpha_p[0];
    const int e0 = idx * 4;
    const int c = (e0 / HW_) & (C_ - 1);
    const float scale = sc[c];
    const float shift = sc[C_ + c];

    float4 v = reinterpret_cast<float4*>(y)[idx];
    float* pv = reinterpret_cast<float*>(&v);
    if (alpha == 1.0f) {
#pragma unroll
        for (int i = 0; i < 4; ++i) {
            float t = pv[i] * scale + shift;
            float sgn = (t > 0.f) ? 1.f : ((t < 0.f) ? -1.f : 0.f);
            pv[i] = t + sgn * POW_EPS;
        }
    } else {
#pragma unroll
        for (int i = 0; i < 4; ++i) {
            float t = pv[i] * scale + shift;
            float sgn = (t > 0.f) ? 1.f : ((t < 0.f) ? -1.f : 0.f);
            pv[i] = sgn * powf(fabsf(t) + POW_EPS, alpha);
        }
    }
    reinterpret_cast<float4*>(y)[idx] = v;
}

extern "C" void kernel_launch(void* const* d_in, const int* in_sizes, int n_in,
                              void* d_out, int out_size, void* d_ws, size_t ws_size,
                              hipStream_t stream)
{
    const float* x      = (const float*)d_in[0];
    const float* weight = (const float*)d_in[1];
    const float* gamma  = (const float*)d_in[2];
    const float* beta   = (const float*)d_in[3];
    const float* alpha  = (const float*)d_in[4];
    float* out = (float*)d_out;

    double* sums = (double*)d_ws;                                // 128 doubles
    float*  sc   = (float*)((char*)d_ws + 128 * sizeof(double)); // 128 floats

    hipMemsetAsync(d_ws, 0, 128 * sizeof(double), stream);

    adder_kernel<<<dim3(64, N_, 4), 256, 0, stream>>>(x, weight, out, sums);
    finalize_kernel<<<1, C_, 0, stream>>>(sums, gamma, beta, sc);

    const int n4 = (N_ * CHW_) / 4;
    apply_kernel<<<n4 / 256, 256, 0, stream>>>(out, sc, alpha);
}